// Round 21
// baseline (59.023 us; speedup 1.0000x reference)
//
#include <hip/hip_runtime.h>
#include <stdint.h>

#define N_ROWS 4096
#define D_DIM  1024
#define N_CAND 8192
#define TEMP_INV 20.0f
#define QSCALE 508.0f
#define OUT_SCALE (TEMP_INV / (QSCALE * QSCALE))

#define BM 128
#define BN 256
#define BK 64
#define NT 16        // K-tiles
#define BUFSZ 24576  // A(8K) + B(16K)

typedef __attribute__((ext_vector_type(4))) int i32x4;

using gvoid = __attribute__((address_space(1))) void;
using lvoid = __attribute__((address_space(3))) void;

#define BAR() __builtin_amdgcn_s_barrier()
#define SCHED0() __builtin_amdgcn_sched_barrier(0)

// ---------------------------------------------------------------------------
// Kernel 1 (v2, unchanged from r20): one WAVE per row, 4 rows per block;
// no LDS, no barriers; quantize q = rint(x*508) clamp +-127. cand = [P; N].
// ---------------------------------------------------------------------------
__global__ __launch_bounds__(256) void prep_kernel(
    const float* __restrict__ s, const float* __restrict__ p,
    const float* __restrict__ ng, unsigned char* __restrict__ s_q,
    unsigned char* __restrict__ cand_q, float* __restrict__ rowsum) {
  const int wid = threadIdx.x >> 6;
  const int l = threadIdx.x & 63;
  const int row = blockIdx.x * 4 + wid;  // 0..12287

  const float* src;
  unsigned char* dst;
  if (row < N_ROWS) {
    src = s + (size_t)row * D_DIM;
    dst = s_q + (size_t)row * D_DIM;
  } else if (row < 2 * N_ROWS) {
    src = p + (size_t)(row - N_ROWS) * D_DIM;
    dst = cand_q + (size_t)(row - N_ROWS) * D_DIM;
  } else {
    src = ng + (size_t)(row - 2 * N_ROWS) * D_DIM;
    dst = cand_q + (size_t)(row - N_ROWS) * D_DIM;
  }

  float4 v[4];
#pragma unroll
  for (int k = 0; k < 4; ++k)
    v[k] = reinterpret_cast<const float4*>(src)[l + 64 * k];

  float ss = 0.0f;
#pragma unroll
  for (int k = 0; k < 4; ++k)
    ss += v[k].x * v[k].x + v[k].y * v[k].y + v[k].z * v[k].z +
          v[k].w * v[k].w;
#pragma unroll
  for (int m = 32; m >= 1; m >>= 1) ss += __shfl_xor(ss, m, 64);

  const float qs = QSCALE / fmaxf(sqrtf(ss), 1e-8f);
  auto q8 = [&](float x) -> unsigned {
    return (unsigned)((int)rintf(fminf(fmaxf(x * qs, -127.0f), 127.0f))) &
           0xffu;
  };
#pragma unroll
  for (int k = 0; k < 4; ++k) {
    const unsigned pk = q8(v[k].x) | (q8(v[k].y) << 8) | (q8(v[k].z) << 16) |
                        (q8(v[k].w) << 24);
    reinterpret_cast<unsigned*>(dst)[l + 64 * k] = pk;
  }

  if (l == 0 && row < N_ROWS) rowsum[row] = 0.0f;
}

// ---------------------------------------------------------------------------
// Kernel 2: fused i8 GEMM + exp-rowsum. KEY CHANGE vs r19: 2 BLOCKS/CU.
// 128x256 tile, 512 thr = 8 waves (2Mx4N), wave 64x64; 3-buffer LDS ring
// 72 KB -> two independent blocks co-resident (144 KB LDS, 16 waves x 128
// unified regs = full pool). All 1-block/CU variants (r13-r19) lockstep at
// a shared barrier -> serial LDS/MFMA phases (~3000 cyc/tile, pipes <35%).
// Independent blocks' barriers interleave -> cross-block overlap (the m114
// mechanism). Inner loop = r19 verbatim: within-tile read<->MFMA
// interleave, stage 2 ahead (3 loads/thread/tile), counted vmcnt(3)
// (0 only at tail), conflict-free slot rotation phys=(g+(rl>>1))&3.
// Ring-3 safety: stage(T+2) targets tile T-1's buffer, last read before
// the barrier that closed tile T-1.
// ---------------------------------------------------------------------------
__global__ __launch_bounds__(512) void gemm_lse_kernel(
    const unsigned char* __restrict__ s_q,
    const unsigned char* __restrict__ cand_q,
    float* __restrict__ rowsum, float* __restrict__ pos) {
  __shared__ __align__(16) unsigned char lds[3 * BUFSZ];  // 72 KB

  const int t = threadIdx.x;
  const int w = t >> 6;
  const int l = t & 63;
  const int g = l >> 4;    // k-slice group: lane's 16B = k g*16..g*16+15
  const int rl = l & 15;   // lane within group
  const int wm = w >> 2;   // 0..1 (wave M half, 64 rows)
  const int wn = w & 3;    // 0..3 (wave N quarter, 64 cols)
  const int slot = (g + (rl >> 1)) & 3;  // phys 16B-slot, lane-constant
  const int rowBase = blockIdx.y * BM;
  const int colBase = blockIdx.x * BN;

  i32x4 acc[4][4] = {};  // 64 AGPR (plain-MFMA path)
  i32x4 af[4];           // 16 VGPR
  i32x4 bf[4];           // 16 VGPR

  // staging: thread t -> phys slot (t&3) of local row (t>>2) (0..127),
  // linear LDS dst t*16; fetch logical slot = ((t&3) - (t>>3)) & 3.
  const int sSlotL = ((t & 3) - (t >> 3)) & 3;
  const unsigned char* gA =
      s_q + (size_t)(rowBase + (t >> 2)) * D_DIM + sSlotL * 16;
  const unsigned char* gB0 =
      cand_q + (size_t)(colBase + (t >> 2)) * D_DIM + sSlotL * 16;
  const unsigned char* gB1 = gB0 + (size_t)128 * D_DIM;

  auto stage = [&](int T, int bufOff) {
    const size_t ko = (size_t)T * 64;
    __builtin_amdgcn_global_load_lds((const gvoid*)(gA + ko),
                                     (lvoid*)(lds + bufOff + t * 16),
                                     16, 0, 0);
    __builtin_amdgcn_global_load_lds((const gvoid*)(gB0 + ko),
                                     (lvoid*)(lds + bufOff + 8192 + t * 16),
                                     16, 0, 0);
    __builtin_amdgcn_global_load_lds((const gvoid*)(gB1 + ko),
                                     (lvoid*)(lds + bufOff + 16384 + t * 16),
                                     16, 0, 0);
  };

  // --- prologue: stage tiles 0,1; wait tile 0 (tile 1's 3 stay in flight).
  int b0 = 0, b1 = BUFSZ, b2 = 2 * BUFSZ;  // uniform ring offsets
  stage(0, b0); stage(1, b1);
  asm volatile("s_waitcnt vmcnt(3)" ::: "memory");
  SCHED0();
  BAR(); SCHED0();

  for (int T = 0; T < NT; ++T) {
    const unsigned char* A = lds + b0;
    const unsigned char* B = A + 8192;

    // minimum reads for the first MFMA row: all bf + af[0]
#pragma unroll
    for (int n = 0; n < 4; ++n) {
      const int r = wn * 64 + n * 16 + rl;
      bf[n] = *reinterpret_cast<const i32x4*>(B + r * 64 + slot * 16);
    }
    af[0] = *reinterpret_cast<const i32x4*>(
        A + (wm * 64 + rl) * 64 + slot * 16);
    if (T + 2 < NT) stage(T + 2, b2);
    SCHED0();

    // row m0
    __builtin_amdgcn_s_setprio(1);
#pragma unroll
    for (int n = 0; n < 4; ++n)
      acc[0][n] = __builtin_amdgcn_mfma_i32_16x16x64_i8(af[0], bf[n],
                                                        acc[0][n], 0, 0, 0);
    __builtin_amdgcn_s_setprio(0);
    SCHED0();
    af[1] = *reinterpret_cast<const i32x4*>(
        A + (wm * 64 + 16 + rl) * 64 + slot * 16);
    SCHED0();

    // row m1
    __builtin_amdgcn_s_setprio(1);
#pragma unroll
    for (int n = 0; n < 4; ++n)
      acc[1][n] = __builtin_amdgcn_mfma_i32_16x16x64_i8(af[1], bf[n],
                                                        acc[1][n], 0, 0, 0);
    __builtin_amdgcn_s_setprio(0);
    SCHED0();
    af[2] = *reinterpret_cast<const i32x4*>(
        A + (wm * 64 + 32 + rl) * 64 + slot * 16);
    SCHED0();

    // row m2
    __builtin_amdgcn_s_setprio(1);
#pragma unroll
    for (int n = 0; n < 4; ++n)
      acc[2][n] = __builtin_amdgcn_mfma_i32_16x16x64_i8(af[2], bf[n],
                                                        acc[2][n], 0, 0, 0);
    __builtin_amdgcn_s_setprio(0);
    SCHED0();
    af[3] = *reinterpret_cast<const i32x4*>(
        A + (wm * 64 + 48 + rl) * 64 + slot * 16);
    SCHED0();

    // row m3
    __builtin_amdgcn_s_setprio(1);
#pragma unroll
    for (int n = 0; n < 4; ++n)
      acc[3][n] = __builtin_amdgcn_mfma_i32_16x16x64_i8(af[3], bf[n],
                                                        acc[3][n], 0, 0, 0);
    __builtin_amdgcn_s_setprio(0);

    if (T + 2 < NT) {
      asm volatile("s_waitcnt vmcnt(3)" ::: "memory");  // T+1 landed
    } else if (T == NT - 2) {
      asm volatile("s_waitcnt vmcnt(0)" ::: "memory");  // tail drain
    }
    SCHED0();
    BAR(); SCHED0();

    const int tmp = b0; b0 = b1; b1 = b2; b2 = tmp;  // rotate ring
  }

  // --- epilogue: sim = acc * 20/508^2; cosine<=1 -> fixed-max LSE at 20.
  // i32 16x16 C/D layout (dtype-independent): col = l&15, row = g*4 + reg.
  __syncthreads();
  float* red = reinterpret_cast<float*>(lds);
  if (t < BM) red[t] = 0.0f;
  __syncthreads();

#pragma unroll
  for (int m = 0; m < 4; ++m) {
#pragma unroll
    for (int j = 0; j < 4; ++j) {
      const int rloc = wm * 64 + m * 16 + g * 4 + j;
      const int rowg = rowBase + rloc;
      float sm = 0.0f;
#pragma unroll
      for (int n = 0; n < 4; ++n) {
        const int colg = colBase + wn * 64 + n * 16 + rl;
        const float simv = (float)acc[m][n][j] * OUT_SCALE;
        if (colg == rowg) pos[rowg] = simv;
        sm += __expf(simv - TEMP_INV);
      }
      sm += __shfl_xor(sm, 1, 64);
      sm += __shfl_xor(sm, 2, 64);
      sm += __shfl_xor(sm, 4, 64);
      sm += __shfl_xor(sm, 8, 64);
      if (rl == 0) atomicAdd(&red[rloc], sm);
    }
  }
  __syncthreads();
  if (t < BM) atomicAdd(&rowsum[rowBase + t], red[t]);
}

// ---------------------------------------------------------------------------
// Kernel 3: loss = mean(20 + log(rowsum) - pos)
// ---------------------------------------------------------------------------
__global__ __launch_bounds__(1024) void loss_kernel(
    const float* __restrict__ rowsum, const float* __restrict__ pos,
    float* __restrict__ out) {
  const int t = threadIdx.x;
  float acc = 0.0f;
  for (int i = t; i < N_ROWS; i += 1024)
    acc += TEMP_INV + logf(rowsum[i]) - pos[i];
#pragma unroll
  for (int m = 32; m >= 1; m >>= 1) acc += __shfl_xor(acc, m, 64);
  __shared__ float red[16];
  const int w = t >> 6, l = t & 63;
  if (l == 0) red[w] = acc;
  __syncthreads();
  if (t == 0) {
    float tot = 0.0f;
#pragma unroll
    for (int i = 0; i < 16; ++i) tot += red[i];
    out[0] = tot / (float)N_ROWS;
  }
}

// ---------------------------------------------------------------------------
extern "C" void kernel_launch(void* const* d_in, const int* in_sizes, int n_in,
                              void* d_out, int out_size, void* d_ws,
                              size_t ws_size, hipStream_t stream) {
  (void)in_sizes; (void)n_in; (void)out_size; (void)ws_size;
  const float* s = (const float*)d_in[0];
  const float* p = (const float*)d_in[1];
  const float* ng = (const float*)d_in[2];

  unsigned char* s_q = (unsigned char*)d_ws;                      // 4 MB
  unsigned char* cand_q = s_q + (size_t)N_ROWS * D_DIM;           // 8 MB
  float* rowsum = (float*)(cand_q + (size_t)N_CAND * D_DIM);      // 16 KB
  float* pos = rowsum + N_ROWS;                                   // 16 KB
  float* out = (float*)d_out;

  prep_kernel<<<dim3(3 * N_ROWS / 4), dim3(256), 0, stream>>>(s, p, ng, s_q,
                                                              cand_q, rowsum);
  gemm_lse_kernel<<<dim3(N_CAND / BN, N_ROWS / BM), dim3(512), 0, stream>>>(
      s_q, cand_q, rowsum, pos);
  loss_kernel<<<dim3(1), dim3(1024), 0, stream>>>(rowsum, pos, out);
}

// Round 22
// 57.839 us; speedup vs baseline: 1.0205x; 1.0205x over previous
//
#include <hip/hip_runtime.h>
#include <stdint.h>

#define N_ROWS 4096
#define D_DIM  1024
#define N_CAND 8192
#define TEMP_INV 20.0f
#define QSCALE 508.0f
#define OUT_SCALE (TEMP_INV / (QSCALE * QSCALE))

#define BM 256
#define BN 256
#define BK 64
#define NT 16  // K-tiles

typedef __attribute__((ext_vector_type(4))) int i32x4;

using gvoid = __attribute__((address_space(1))) void;
using lvoid = __attribute__((address_space(3))) void;

#define BAR() __builtin_amdgcn_s_barrier()
#define SCHED0() __builtin_amdgcn_sched_barrier(0)

// ---------------------------------------------------------------------------
// Kernel 1: one WAVE per row, 4 rows per 256-thr block -- no LDS, no
// barriers. Lane l holds 16 elems (4x float4, wave-contiguous 1 KB loads);
// sum-sq via __shfl_xor; quantize q = rint(x*508) clamp +-127; i8 stores
// wave-contiguous. cand = [P; N]. Zeroes rowsum. (r20-measured: ~10 us,
// at the ~9.5 us HBM floor for 60 MB.)
// ---------------------------------------------------------------------------
__global__ __launch_bounds__(256) void prep_kernel(
    const float* __restrict__ s, const float* __restrict__ p,
    const float* __restrict__ ng, unsigned char* __restrict__ s_q,
    unsigned char* __restrict__ cand_q, float* __restrict__ rowsum) {
  const int wid = threadIdx.x >> 6;
  const int l = threadIdx.x & 63;
  const int row = blockIdx.x * 4 + wid;  // 0..12287

  const float* src;
  unsigned char* dst;
  if (row < N_ROWS) {
    src = s + (size_t)row * D_DIM;
    dst = s_q + (size_t)row * D_DIM;
  } else if (row < 2 * N_ROWS) {
    src = p + (size_t)(row - N_ROWS) * D_DIM;
    dst = cand_q + (size_t)(row - N_ROWS) * D_DIM;
  } else {
    src = ng + (size_t)(row - 2 * N_ROWS) * D_DIM;
    dst = cand_q + (size_t)(row - N_ROWS) * D_DIM;
  }

  float4 v[4];
#pragma unroll
  for (int k = 0; k < 4; ++k)
    v[k] = reinterpret_cast<const float4*>(src)[l + 64 * k];

  float ss = 0.0f;
#pragma unroll
  for (int k = 0; k < 4; ++k)
    ss += v[k].x * v[k].x + v[k].y * v[k].y + v[k].z * v[k].z +
          v[k].w * v[k].w;
#pragma unroll
  for (int m = 32; m >= 1; m >>= 1) ss += __shfl_xor(ss, m, 64);

  const float qs = QSCALE / fmaxf(sqrtf(ss), 1e-8f);
  auto q8 = [&](float x) -> unsigned {
    return (unsigned)((int)rintf(fminf(fmaxf(x * qs, -127.0f), 127.0f))) &
           0xffu;
  };
#pragma unroll
  for (int k = 0; k < 4; ++k) {
    const unsigned pk = q8(v[k].x) | (q8(v[k].y) << 8) | (q8(v[k].z) << 16) |
                        (q8(v[k].w) << 24);
    reinterpret_cast<unsigned*>(dst)[l + 64 * k] = pk;
  }

  if (l == 0 && row < N_ROWS) rowsum[row] = 0.0f;
}

// ---------------------------------------------------------------------------
// Kernel 2: fused i8 GEMM + exp-rowsum -- the session-best r19/r20 kernel
// (measured 40.6 us, MfmaUtil 32%, 0 bank conflicts, no spill; 8 structural
// variants bracketed this as the latency plateau). 256x256 tile, BK=64,
// 1024 thr = 16 waves (4Mx4N), wave 64x64 = 4x4 frags of
// mfma_i32_16x16x64_i8 (acc 64 AGPR + 64 arch = 128 unified -> 4 waves/
// SIMD). 4-buffer LDS ring (128 KB), 2 gload_lds/thread/tile staged 2
// ahead, one barrier per K-tile, counted vmcnt(2) (0 only at tail),
// within-tile read<->MFMA interleave ({bf,af0} -> {MFMA row m | read
// af[m+1]} pinned by sched_barrier(0)), conflict-free LDS slot rotation
// phys=(g+(rl>>1))&3 with inverse-permuted global source.
// ---------------------------------------------------------------------------
__global__ __launch_bounds__(1024) void gemm_lse_kernel(
    const unsigned char* __restrict__ s_q,
    const unsigned char* __restrict__ cand_q,
    float* __restrict__ rowsum, float* __restrict__ pos) {
  __shared__ __align__(16) unsigned char lds[4 * 32768];  // 4 x (A16K|B16K)

  const int t = threadIdx.x;
  const int w = t >> 6;
  const int l = t & 63;
  const int g = l >> 4;
  const int rl = l & 15;
  const int wm = w >> 2;
  const int wn = w & 3;
  const int slot = (g + (rl >> 1)) & 3;
  const int rowBase = blockIdx.y * BM;
  const int colBase = blockIdx.x * BN;

  i32x4 acc[4][4] = {};
  i32x4 af[4];
  i32x4 bf[4];

  const int sSlotL = ((t & 3) - (t >> 3)) & 3;
  const unsigned char* gA =
      s_q + (size_t)(rowBase + (t >> 2)) * D_DIM + sSlotL * 16;
  const unsigned char* gB =
      cand_q + (size_t)(colBase + (t >> 2)) * D_DIM + sSlotL * 16;

  auto stage = [&](int T) {
    const int buf = (T & 3) * 32768;
    const size_t ko = (size_t)T * 64;
    __builtin_amdgcn_global_load_lds((const gvoid*)(gA + ko),
                                     (lvoid*)(lds + buf + t * 16), 16, 0, 0);
    __builtin_amdgcn_global_load_lds(
        (const gvoid*)(gB + ko),
        (lvoid*)(lds + buf + 16384 + t * 16), 16, 0, 0);
  };

  stage(0); stage(1);
  asm volatile("s_waitcnt vmcnt(2)" ::: "memory");
  SCHED0();
  BAR(); SCHED0();

  for (int T = 0; T < NT; ++T) {
    const unsigned char* A = lds + (T & 3) * 32768;
    const unsigned char* B = A + 16384;

#pragma unroll
    for (int n = 0; n < 4; ++n) {
      const int r = wn * 64 + n * 16 + rl;
      bf[n] = *reinterpret_cast<const i32x4*>(B + r * 64 + slot * 16);
    }
    af[0] = *reinterpret_cast<const i32x4*>(
        A + (wm * 64 + rl) * 64 + slot * 16);
    if (T + 2 < NT) stage(T + 2);
    SCHED0();

    __builtin_amdgcn_s_setprio(1);
#pragma unroll
    for (int n = 0; n < 4; ++n)
      acc[0][n] = __builtin_amdgcn_mfma_i32_16x16x64_i8(af[0], bf[n],
                                                        acc[0][n], 0, 0, 0);
    __builtin_amdgcn_s_setprio(0);
    SCHED0();
    af[1] = *reinterpret_cast<const i32x4*>(
        A + (wm * 64 + 16 + rl) * 64 + slot * 16);
    SCHED0();

    __builtin_amdgcn_s_setprio(1);
#pragma unroll
    for (int n = 0; n < 4; ++n)
      acc[1][n] = __builtin_amdgcn_mfma_i32_16x16x64_i8(af[1], bf[n],
                                                        acc[1][n], 0, 0, 0);
    __builtin_amdgcn_s_setprio(0);
    SCHED0();
    af[2] = *reinterpret_cast<const i32x4*>(
        A + (wm * 64 + 32 + rl) * 64 + slot * 16);
    SCHED0();

    __builtin_amdgcn_s_setprio(1);
#pragma unroll
    for (int n = 0; n < 4; ++n)
      acc[2][n] = __builtin_amdgcn_mfma_i32_16x16x64_i8(af[2], bf[n],
                                                        acc[2][n], 0, 0, 0);
    __builtin_amdgcn_s_setprio(0);
    SCHED0();
    af[3] = *reinterpret_cast<const i32x4*>(
        A + (wm * 64 + 48 + rl) * 64 + slot * 16);
    SCHED0();

    __builtin_amdgcn_s_setprio(1);
#pragma unroll
    for (int n = 0; n < 4; ++n)
      acc[3][n] = __builtin_amdgcn_mfma_i32_16x16x64_i8(af[3], bf[n],
                                                        acc[3][n], 0, 0, 0);
    __builtin_amdgcn_s_setprio(0);

    if (T + 2 < NT) {
      asm volatile("s_waitcnt vmcnt(2)" ::: "memory");
    } else if (T == NT - 2) {
      asm volatile("s_waitcnt vmcnt(0)" ::: "memory");
    }
    SCHED0();
    BAR(); SCHED0();
  }

  // epilogue: sim = acc * 20/508^2; cosine<=1 -> fixed-max LSE at 20.
  // i32 16x16 C/D layout (dtype-independent): col = l&15, row = g*4 + reg.
  __syncthreads();
  float* red = reinterpret_cast<float*>(lds);
  if (t < BM) red[t] = 0.0f;
  __syncthreads();

#pragma unroll
  for (int m = 0; m < 4; ++m) {
#pragma unroll
    for (int j = 0; j < 4; ++j) {
      const int rloc = wm * 64 + m * 16 + g * 4 + j;
      const int rowg = rowBase + rloc;
      float sm = 0.0f;
#pragma unroll
      for (int n = 0; n < 4; ++n) {
        const int colg = colBase + wn * 64 + n * 16 + rl;
        const float simv = (float)acc[m][n][j] * OUT_SCALE;
        if (colg == rowg) pos[rowg] = simv;
        sm += __expf(simv - TEMP_INV);
      }
      sm += __shfl_xor(sm, 1, 64);
      sm += __shfl_xor(sm, 2, 64);
      sm += __shfl_xor(sm, 4, 64);
      sm += __shfl_xor(sm, 8, 64);
      if (rl == 0) atomicAdd(&red[rloc], sm);
    }
  }
  __syncthreads();
  if (t < BM) atomicAdd(&rowsum[rowBase + t], red[t]);
}

// ---------------------------------------------------------------------------
// Kernel 3: loss = mean(20 + log(rowsum) - pos)
// ---------------------------------------------------------------------------
__global__ __launch_bounds__(1024) void loss_kernel(
    const float* __restrict__ rowsum, const float* __restrict__ pos,
    float* __restrict__ out) {
  const int t = threadIdx.x;
  float acc = 0.0f;
  for (int i = t; i < N_ROWS; i += 1024)
    acc += TEMP_INV + logf(rowsum[i]) - pos[i];
#pragma unroll
  for (int m = 32; m >= 1; m >>= 1) acc += __shfl_xor(acc, m, 64);
  __shared__ float red[16];
  const int w = t >> 6, l = t & 63;
  if (l == 0) red[w] = acc;
  __syncthreads();
  if (t == 0) {
    float tot = 0.0f;
#pragma unroll
    for (int i = 0; i < 16; ++i) tot += red[i];
    out[0] = tot / (float)N_ROWS;
  }
}

// ---------------------------------------------------------------------------
extern "C" void kernel_launch(void* const* d_in, const int* in_sizes, int n_in,
                              void* d_out, int out_size, void* d_ws,
                              size_t ws_size, hipStream_t stream) {
  (void)in_sizes; (void)n_in; (void)out_size; (void)ws_size;
  const float* s = (const float*)d_in[0];
  const float* p = (const float*)d_in[1];
  const float* ng = (const float*)d_in[2];

  unsigned char* s_q = (unsigned char*)d_ws;                      // 4 MB
  unsigned char* cand_q = s_q + (size_t)N_ROWS * D_DIM;           // 8 MB
  float* rowsum = (float*)(cand_q + (size_t)N_CAND * D_DIM);      // 16 KB
  float* pos = rowsum + N_ROWS;                                   // 16 KB
  float* out = (float*)d_out;

  prep_kernel<<<dim3(3 * N_ROWS / 4), dim3(256), 0, stream>>>(s, p, ng, s_q,
                                                              cand_q, rowsum);
  gemm_lse_kernel<<<dim3(N_CAND / BN, N_ROWS / BM), dim3(1024), 0, stream>>>(
      s_q, cand_q, rowsum, pos);
  loss_kernel<<<dim3(1), dim3(1024), 0, stream>>>(rowsum, pos, out);
}